// Round 3
// baseline (214.839 us; speedup 1.0000x reference)
//
#include <hip/hip_runtime.h>

#define NROWS 12288
#define BSZ   4096
#define DIM   128
#define NSTRIPS 12            // 768 cols per block (12 strips x 64 cols)

typedef __bf16 bf16x8 __attribute__((ext_vector_type(8)));
typedef float  f32x4  __attribute__((ext_vector_type(4)));

__device__ __forceinline__ unsigned short f2bf(float f) {
  unsigned int u = __float_as_uint(f);
  u = u + 0x7FFFu + ((u >> 16) & 1u);   // round-to-nearest-even
  return (unsigned short)(u >> 16);
}
__device__ __forceinline__ float bf2f(unsigned short h) {
  return __uint_as_float(((unsigned int)h) << 16);
}

// ---------------------------------------------------------------------------
// Kernel 1 (fused prep + posmax): one wave per triplet index i.
// Reads a_i, p_i, n_i once; emits bf16 rows for all 3 panels, sq of rounded
// values, exact-fp32 pos_max^2 for all 3 rows, per-index reg partial (no
// single-address atomics), inits negbits. Grid 1024 x 256.
// ---------------------------------------------------------------------------
__global__ void prep_k(const float* __restrict__ a, const float* __restrict__ p,
                       const float* __restrict__ nn,
                       unsigned short* __restrict__ embh, float* __restrict__ sq,
                       unsigned int* __restrict__ negbits,
                       float* __restrict__ posmax2, float* __restrict__ regpart) {
  const int w = threadIdx.x >> 6, lane = threadIdx.x & 63;
  const int i = blockIdx.x * 4 + w;
  const float2 av = reinterpret_cast<const float2*>(a  + (size_t)i * DIM)[lane];
  const float2 pv = reinterpret_cast<const float2*>(p  + (size_t)i * DIM)[lane];
  const float2 nv = reinterpret_cast<const float2*>(nn + (size_t)i * DIM)[lane];

  const unsigned short ha0 = f2bf(av.x), ha1 = f2bf(av.y);
  const unsigned short hp0 = f2bf(pv.x), hp1 = f2bf(pv.y);
  const unsigned short hn0 = f2bf(nv.x), hn1 = f2bf(nv.y);
  reinterpret_cast<ushort2*>(embh + (size_t)i * DIM)[lane]             = make_ushort2(ha0, ha1);
  reinterpret_cast<ushort2*>(embh + (size_t)(BSZ + i) * DIM)[lane]     = make_ushort2(hp0, hp1);
  reinterpret_cast<ushort2*>(embh + (size_t)(2 * BSZ + i) * DIM)[lane] = make_ushort2(hn0, hn1);

  // sq of ROUNDED values (so the GEMM-based d2 is consistent & >= 0)
  float rax = bf2f(ha0), ray = bf2f(ha1);
  float rpx = bf2f(hp0), rpy = bf2f(hp1);
  float rnx = bf2f(hn0), rny = bf2f(hn1);
  float sa = rax * rax + ray * ray;
  float sp = rpx * rpx + rpy * rpy;
  float sn = rnx * rnx + rny * rny;

  // reg from exact values
  float t0 = fabsf(av.x) - 1.f, t1 = fabsf(av.y) - 1.f;
  float t2 = fabsf(pv.x) - 1.f, t3 = fabsf(pv.y) - 1.f;
  float t4 = fabsf(nv.x) - 1.f, t5 = fabsf(nv.y) - 1.f;
  float rg = t0 * t0 + t1 * t1 + t2 * t2 + t3 * t3 + t4 * t4 + t5 * t5;

  // pos distances, exact fp32
  float dx, dy;
  dx = av.x - pv.x; dy = av.y - pv.y; float dap = dx * dx + dy * dy;
  dx = av.x - nv.x; dy = av.y - nv.y; float dan = dx * dx + dy * dy;
  dx = pv.x - nv.x; dy = pv.y - nv.y; float dpn = dx * dx + dy * dy;

  for (int m = 32; m; m >>= 1) {
    sa  += __shfl_xor(sa, m);  sp  += __shfl_xor(sp, m);  sn  += __shfl_xor(sn, m);
    rg  += __shfl_xor(rg, m);
    dap += __shfl_xor(dap, m); dan += __shfl_xor(dan, m); dpn += __shfl_xor(dpn, m);
  }
  if (lane == 0) {
    sq[i] = sa; sq[BSZ + i] = sp; sq[2 * BSZ + i] = sn;
    negbits[i] = negbits[BSZ + i] = negbits[2 * BSZ + i] = 0x7F800000u;  // +inf
    posmax2[i]           = fmaxf(dap, dan);
    posmax2[BSZ + i]     = fmaxf(dap, dpn);
    posmax2[2 * BSZ + i] = fmaxf(dan, dpn);
    regpart[i] = rg;
  }
}

// ---------------------------------------------------------------------------
// Kernel 2: neg_min^2. Fused GEMM (E*E^T, bf16 MFMA 16x16x32) + row-min.
// Block = 128 rows x 768 cols. A-tile (128x128) fully register-resident.
// NO LDS AT ALL: for 16x16x32, the B-fragment B[k=q*8+j][n=lane&15] is
// exactly what lane (c16,q) loads from row-major embh — round 2's LDS
// round-trip was an identity and only added waitcnt chains.
// Depth-2 register prefetch of B strips. 4 waves partition columns, no
// barriers. Grid (96, 16) = 1536 blocks = 3 full residency rounds @ 2/CU.
// ---------------------------------------------------------------------------
__global__ __launch_bounds__(256, 2) void negmin_k(
    const unsigned short* __restrict__ embh,
    const float* __restrict__ sq,
    unsigned int* __restrict__ negbits) {
  const int tid  = threadIdx.x;
  const int w    = tid >> 6;
  const int lane = tid & 63;
  const int c16  = lane & 15;          // col-within-strip / A-row-within-tile
  const int q    = lane >> 4;          // k-quad
  const int rowBase  = blockIdx.x * 128;
  const int colBase0 = blockIdx.y * (NSTRIPS * 64);

  // A fragments: rows [rowBase, rowBase+128), all K=128. 8 mtiles x 4 ksteps.
  // A[m=lane&15][k=q*8+j] for 16x16x32.
  bf16x8 afrag[8][4];
  {
    const char* abase = (const char*)embh + (size_t)(rowBase + c16) * 256 + q * 16;
#pragma unroll
    for (int mt = 0; mt < 8; ++mt)
#pragma unroll
      for (int ks = 0; ks < 4; ++ks)
        afrag[mt][ks] = *reinterpret_cast<const bf16x8*>(abase + mt * (16 * 256) + ks * 64);
  }

  float minv[8][4];
#pragma unroll
  for (int mt = 0; mt < 8; ++mt)
#pragma unroll
    for (int r = 0; r < 4; ++r) minv[mt][r] = __builtin_inff();

  // B strip staging: stg[s][ks] is directly the B-fragment for kstep ks.
  union { uint4 u; bf16x8 v; } stg[2][4];
  float sqstg[2];
  const char* gqoff = (const char*)embh + q * 16;
  auto load_strip = [&](int c, int s) {
    const int colStart = colBase0 + c * 64 + w * 16;
    const char* gp = gqoff + (size_t)(colStart + c16) * 256;
#pragma unroll
    for (int pp = 0; pp < 4; ++pp)
      stg[s][pp].u = *reinterpret_cast<const uint4*>(gp + pp * 64);
    sqstg[s] = sq[colStart + c16];
  };

  load_strip(0, 0);
  load_strip(1, 1);

  for (int c = 0; c < NSTRIPS; ++c) {
    const int s = c & 1;
    bf16x8 bfr[4];
#pragma unroll
    for (int ks = 0; ks < 4; ++ks) bfr[ks] = stg[s][ks].v;
    const float sqb = sqstg[s];
    if (c + 2 < NSTRIPS) load_strip(c + 2, s);   // depth-2 prefetch

    f32x4 acc[8] = {};
#pragma unroll
    for (int ks = 0; ks < 4; ++ks)
#pragma unroll
      for (int mt = 0; mt < 8; ++mt)
        acc[mt] = __builtin_amdgcn_mfma_f32_16x16x32_bf16(afrag[mt][ks], bfr[ks], acc[mt], 0, 0, 0);

    // Epilogue: track min over j of (sq_j - 2*dot). sq_i added at the end.
    // Exclusion (j == i mod 4096) only possible when dd in [0,128) U (4080,4096).
    const int colStart = colBase0 + c * 64 + w * 16;
    const int dd = (colStart - rowBase) & 4095;
    if (dd < 128 || dd > 4080) {
      const int lv = dd + c16 - q * 4;
#pragma unroll
      for (int mt = 0; mt < 8; ++mt)
#pragma unroll
        for (int r = 0; r < 4; ++r) {
          float v = fmaf(-2.f, acc[mt][r], sqb);
          const int K = mt * 16 + r;
          if (lv == K || lv == K + 4096) v = __builtin_inff();
          minv[mt][r] = fminf(minv[mt][r], v);
        }
    } else {
#pragma unroll
      for (int mt = 0; mt < 8; ++mt)
#pragma unroll
        for (int r = 0; r < 4; ++r)
          minv[mt][r] = fminf(minv[mt][r], fmaf(-2.f, acc[mt][r], sqb));
    }
  }

  // Reduce over the 16 column-lanes sharing each row, then atomicMin (uint
  // bits are order-preserving for floats >= 0). Distinct addresses per row.
#pragma unroll
  for (int mt = 0; mt < 8; ++mt)
#pragma unroll
    for (int r = 0; r < 4; ++r) {
      float v = minv[mt][r];
      v = fminf(v, __shfl_xor(v, 1));
      v = fminf(v, __shfl_xor(v, 2));
      v = fminf(v, __shfl_xor(v, 4));
      v = fminf(v, __shfl_xor(v, 8));
      if (c16 == 0) {
        const int row = rowBase + mt * 16 + q * 4 + r;  // C/D: row=(lane>>4)*4+r
        float d2 = sq[row] + v;
        d2 = fmaxf(d2, 0.f);
        atomicMin(&negbits[row], __float_as_uint(d2));
      }
    }
}

// ---------------------------------------------------------------------------
// Kernel 3: final scalar. loss = mean(relu(sqrt(pos2)-sqrt(neg2)+margin)) +
// alpha * sum(regpart) / (3*B*D). Single block, 1024 threads.
// ---------------------------------------------------------------------------
__global__ void final_k(const float* __restrict__ posmax2,
                        const unsigned int* __restrict__ negbits,
                        const float* __restrict__ regpart, float* __restrict__ out) {
  __shared__ float red[16], redr[16];
  const int tid = threadIdx.x;  // 1024
  float s = 0.f;
  for (int i = tid; i < NROWS; i += 1024) {
    const float pm = sqrtf(posmax2[i]);
    const float nm = sqrtf(__uint_as_float(negbits[i]));
    s += fmaxf(pm - nm + 0.4f, 0.f);
  }
  float rg = 0.f;
  for (int i = tid; i < BSZ; i += 1024) rg += regpart[i];
  for (int m = 32; m; m >>= 1) { s += __shfl_xor(s, m); rg += __shfl_xor(rg, m); }
  if ((tid & 63) == 0) { red[tid >> 6] = s; redr[tid >> 6] = rg; }
  __syncthreads();
  if (tid == 0) {
    float t = 0.f, tr = 0.f;
#pragma unroll
    for (int k = 0; k < 16; ++k) { t += red[k]; tr += redr[k]; }
    out[0] = t / (float)NROWS + 0.01f * (tr / (float)(NROWS * DIM));
  }
}

// ---------------------------------------------------------------------------
extern "C" void kernel_launch(void* const* d_in, const int* in_sizes, int n_in,
                              void* d_out, int out_size, void* d_ws, size_t ws_size,
                              hipStream_t stream) {
  const float* a  = (const float*)d_in[0];
  const float* p  = (const float*)d_in[1];
  const float* nn = (const float*)d_in[2];
  float* out = (float*)d_out;
  char* ws = (char*)d_ws;

  const size_t EMBH_BYTES = (size_t)NROWS * DIM * 2;       // 3,145,728
  unsigned short* embh    = (unsigned short*)ws;
  float*          sq      = (float*)(ws + EMBH_BYTES);
  unsigned int*   negbit  = (unsigned int*)(ws + EMBH_BYTES + (size_t)NROWS * 4);
  float*          pos2    = (float*)(ws + EMBH_BYTES + (size_t)NROWS * 8);
  float*          regpart = (float*)(ws + EMBH_BYTES + (size_t)NROWS * 12);

  prep_k<<<BSZ / 4, 256, 0, stream>>>(a, p, nn, embh, sq, negbit, pos2, regpart);
  negmin_k<<<dim3(96, 16), 256, 0, stream>>>(embh, sq, negbit);
  final_k<<<1, 1024, 0, stream>>>(pos2, negbit, regpart, out);
}

// Round 4
// 164.180 us; speedup vs baseline: 1.3086x; 1.3086x over previous
//
#include <hip/hip_runtime.h>

#define NROWS 12288
#define BSZ   4096
#define DIM   128
#define NSTRIPS 12            // 768 cols per block (12 strips x 64 cols)

typedef __bf16 bf16x8 __attribute__((ext_vector_type(8)));
typedef float  f32x4  __attribute__((ext_vector_type(4)));

__device__ __forceinline__ unsigned short f2bf(float f) {
  unsigned int u = __float_as_uint(f);
  u = u + 0x7FFFu + ((u >> 16) & 1u);   // round-to-nearest-even
  return (unsigned short)(u >> 16);
}
__device__ __forceinline__ float bf2f(unsigned short h) {
  return __uint_as_float(((unsigned int)h) << 16);
}

// ---------------------------------------------------------------------------
// Kernel 1 (fused prep + posmax): one wave per triplet index i.
// ---------------------------------------------------------------------------
__global__ void prep_k(const float* __restrict__ a, const float* __restrict__ p,
                       const float* __restrict__ nn,
                       unsigned short* __restrict__ embh, float* __restrict__ sq,
                       unsigned int* __restrict__ negbits,
                       float* __restrict__ posmax2, float* __restrict__ regpart) {
  const int w = threadIdx.x >> 6, lane = threadIdx.x & 63;
  const int i = blockIdx.x * 4 + w;
  const float2 av = reinterpret_cast<const float2*>(a  + (size_t)i * DIM)[lane];
  const float2 pv = reinterpret_cast<const float2*>(p  + (size_t)i * DIM)[lane];
  const float2 nv = reinterpret_cast<const float2*>(nn + (size_t)i * DIM)[lane];

  const unsigned short ha0 = f2bf(av.x), ha1 = f2bf(av.y);
  const unsigned short hp0 = f2bf(pv.x), hp1 = f2bf(pv.y);
  const unsigned short hn0 = f2bf(nv.x), hn1 = f2bf(nv.y);
  reinterpret_cast<ushort2*>(embh + (size_t)i * DIM)[lane]             = make_ushort2(ha0, ha1);
  reinterpret_cast<ushort2*>(embh + (size_t)(BSZ + i) * DIM)[lane]     = make_ushort2(hp0, hp1);
  reinterpret_cast<ushort2*>(embh + (size_t)(2 * BSZ + i) * DIM)[lane] = make_ushort2(hn0, hn1);

  // sq of ROUNDED values (so the GEMM-based d2 is consistent & >= 0)
  float rax = bf2f(ha0), ray = bf2f(ha1);
  float rpx = bf2f(hp0), rpy = bf2f(hp1);
  float rnx = bf2f(hn0), rny = bf2f(hn1);
  float sa = rax * rax + ray * ray;
  float sp = rpx * rpx + rpy * rpy;
  float sn = rnx * rnx + rny * rny;

  // reg from exact values
  float t0 = fabsf(av.x) - 1.f, t1 = fabsf(av.y) - 1.f;
  float t2 = fabsf(pv.x) - 1.f, t3 = fabsf(pv.y) - 1.f;
  float t4 = fabsf(nv.x) - 1.f, t5 = fabsf(nv.y) - 1.f;
  float rg = t0 * t0 + t1 * t1 + t2 * t2 + t3 * t3 + t4 * t4 + t5 * t5;

  // pos distances, exact fp32
  float dx, dy;
  dx = av.x - pv.x; dy = av.y - pv.y; float dap = dx * dx + dy * dy;
  dx = av.x - nv.x; dy = av.y - nv.y; float dan = dx * dx + dy * dy;
  dx = pv.x - nv.x; dy = pv.y - nv.y; float dpn = dx * dx + dy * dy;

  for (int m = 32; m; m >>= 1) {
    sa  += __shfl_xor(sa, m);  sp  += __shfl_xor(sp, m);  sn  += __shfl_xor(sn, m);
    rg  += __shfl_xor(rg, m);
    dap += __shfl_xor(dap, m); dan += __shfl_xor(dan, m); dpn += __shfl_xor(dpn, m);
  }
  if (lane == 0) {
    sq[i] = sa; sq[BSZ + i] = sp; sq[2 * BSZ + i] = sn;
    negbits[i] = negbits[BSZ + i] = negbits[2 * BSZ + i] = 0x7F800000u;  // +inf
    posmax2[i]           = fmaxf(dap, dan);
    posmax2[BSZ + i]     = fmaxf(dap, dpn);
    posmax2[2 * BSZ + i] = fmaxf(dan, dpn);
    regpart[i] = rg;
  }
}

// ---------------------------------------------------------------------------
// Kernel 2: neg_min^2. Fused GEMM (E*E^T, bf16 MFMA 16x16x32) + row-min.
// Block = 128 rows x 768 cols. A-tile (128x128) register-resident.
// No LDS; B-fragments load directly from row-major embh (layout identity).
// DEPTH-1 staging only: round 3's depth-2 (+16 regs) pushed past the
// 256-reg budget of (256,2) and spilled 88 VGPRs to scratch (WRITE_SIZE
// 14 MB -> 137 MB). Budget now: afrag 128 + acc 32 + minv 32 + stg 16 +
// bfr 16 + addr ~15 = ~210 <= 256.
// ---------------------------------------------------------------------------
__global__ __launch_bounds__(256, 2) void negmin_k(
    const unsigned short* __restrict__ embh,
    const float* __restrict__ sq,
    unsigned int* __restrict__ negbits) {
  const int tid  = threadIdx.x;
  const int w    = tid >> 6;
  const int lane = tid & 63;
  const int c16  = lane & 15;          // col-within-strip / A-row-within-tile
  const int q    = lane >> 4;          // k-quad
  const int rowBase  = blockIdx.x * 128;
  const int colBase0 = blockIdx.y * (NSTRIPS * 64);

  // A fragments: rows [rowBase, rowBase+128), all K=128. 8 mtiles x 4 ksteps.
  // A[m=lane&15][k=q*8+j] for 16x16x32.
  bf16x8 afrag[8][4];
  {
    const char* abase = (const char*)embh + (size_t)(rowBase + c16) * 256 + q * 16;
#pragma unroll
    for (int mt = 0; mt < 8; ++mt)
#pragma unroll
      for (int ks = 0; ks < 4; ++ks)
        afrag[mt][ks] = *reinterpret_cast<const bf16x8*>(abase + mt * (16 * 256) + ks * 64);
  }

  float minv[8][4];
#pragma unroll
  for (int mt = 0; mt < 8; ++mt)
#pragma unroll
    for (int r = 0; r < 4; ++r) minv[mt][r] = __builtin_inff();

  // Single staging buffer; stg[ks] is directly the B-fragment for kstep ks.
  union { uint4 u; bf16x8 v; } stg[4];
  float sqstg;
  const char* gqoff = (const char*)embh + q * 16;
  auto load_strip = [&](int c) {
    const int colStart = colBase0 + c * 64 + w * 16;
    const char* gp = gqoff + (size_t)(colStart + c16) * 256;
#pragma unroll
    for (int pp = 0; pp < 4; ++pp)
      stg[pp].u = *reinterpret_cast<const uint4*>(gp + pp * 64);
    sqstg = sq[colStart + c16];
  };

  load_strip(0);

  for (int c = 0; c < NSTRIPS; ++c) {
    // Consume staged strip into working regs, then immediately issue the
    // next strip's loads so they overlap this strip's MFMA + epilogue.
    bf16x8 bfr[4];
#pragma unroll
    for (int ks = 0; ks < 4; ++ks) bfr[ks] = stg[ks].v;
    const float sqb = sqstg;
    if (c + 1 < NSTRIPS) load_strip(c + 1);

    f32x4 acc[8] = {};
#pragma unroll
    for (int ks = 0; ks < 4; ++ks)
#pragma unroll
      for (int mt = 0; mt < 8; ++mt)
        acc[mt] = __builtin_amdgcn_mfma_f32_16x16x32_bf16(afrag[mt][ks], bfr[ks], acc[mt], 0, 0, 0);

    // Epilogue: track min over j of (sq_j - 2*dot). sq_i added at the end.
    // Exclusion (j == i mod 4096) only possible when dd in [0,128) U (4080,4096).
    const int colStart = colBase0 + c * 64 + w * 16;
    const int dd = (colStart - rowBase) & 4095;
    if (dd < 128 || dd > 4080) {
      const int lv = dd + c16 - q * 4;
#pragma unroll
      for (int mt = 0; mt < 8; ++mt)
#pragma unroll
        for (int r = 0; r < 4; ++r) {
          float v = fmaf(-2.f, acc[mt][r], sqb);
          const int K = mt * 16 + r;
          if (lv == K || lv == K + 4096) v = __builtin_inff();
          minv[mt][r] = fminf(minv[mt][r], v);
        }
    } else {
#pragma unroll
      for (int mt = 0; mt < 8; ++mt)
#pragma unroll
        for (int r = 0; r < 4; ++r)
          minv[mt][r] = fminf(minv[mt][r], fmaf(-2.f, acc[mt][r], sqb));
    }
  }

  // Reduce over the 16 column-lanes sharing each row, then atomicMin (uint
  // bits are order-preserving for floats >= 0). Distinct addresses per row.
#pragma unroll
  for (int mt = 0; mt < 8; ++mt)
#pragma unroll
    for (int r = 0; r < 4; ++r) {
      float v = minv[mt][r];
      v = fminf(v, __shfl_xor(v, 1));
      v = fminf(v, __shfl_xor(v, 2));
      v = fminf(v, __shfl_xor(v, 4));
      v = fminf(v, __shfl_xor(v, 8));
      if (c16 == 0) {
        const int row = rowBase + mt * 16 + q * 4 + r;  // C/D: row=(lane>>4)*4+r
        float d2 = sq[row] + v;
        d2 = fmaxf(d2, 0.f);
        atomicMin(&negbits[row], __float_as_uint(d2));
      }
    }
}

// ---------------------------------------------------------------------------
// Kernel 3: final scalar reduction. Single block, 1024 threads.
// ---------------------------------------------------------------------------
__global__ void final_k(const float* __restrict__ posmax2,
                        const unsigned int* __restrict__ negbits,
                        const float* __restrict__ regpart, float* __restrict__ out) {
  __shared__ float red[16], redr[16];
  const int tid = threadIdx.x;  // 1024
  float s = 0.f;
  for (int i = tid; i < NROWS; i += 1024) {
    const float pm = sqrtf(posmax2[i]);
    const float nm = sqrtf(__uint_as_float(negbits[i]));
    s += fmaxf(pm - nm + 0.4f, 0.f);
  }
  float rg = 0.f;
  for (int i = tid; i < BSZ; i += 1024) rg += regpart[i];
  for (int m = 32; m; m >>= 1) { s += __shfl_xor(s, m); rg += __shfl_xor(rg, m); }
  if ((tid & 63) == 0) { red[tid >> 6] = s; redr[tid >> 6] = rg; }
  __syncthreads();
  if (tid == 0) {
    float t = 0.f, tr = 0.f;
#pragma unroll
    for (int k = 0; k < 16; ++k) { t += red[k]; tr += redr[k]; }
    out[0] = t / (float)NROWS + 0.01f * (tr / (float)(NROWS * DIM));
  }
}

// ---------------------------------------------------------------------------
extern "C" void kernel_launch(void* const* d_in, const int* in_sizes, int n_in,
                              void* d_out, int out_size, void* d_ws, size_t ws_size,
                              hipStream_t stream) {
  const float* a  = (const float*)d_in[0];
  const float* p  = (const float*)d_in[1];
  const float* nn = (const float*)d_in[2];
  float* out = (float*)d_out;
  char* ws = (char*)d_ws;

  const size_t EMBH_BYTES = (size_t)NROWS * DIM * 2;       // 3,145,728
  unsigned short* embh    = (unsigned short*)ws;
  float*          sq      = (float*)(ws + EMBH_BYTES);
  unsigned int*   negbit  = (unsigned int*)(ws + EMBH_BYTES + (size_t)NROWS * 4);
  float*          pos2    = (float*)(ws + EMBH_BYTES + (size_t)NROWS * 8);
  float*          regpart = (float*)(ws + EMBH_BYTES + (size_t)NROWS * 12);

  prep_k<<<BSZ / 4, 256, 0, stream>>>(a, p, nn, embh, sq, negbit, pos2, regpart);
  negmin_k<<<dim3(96, 16), 256, 0, stream>>>(embh, sq, negbit);
  final_k<<<1, 1024, 0, stream>>>(pos2, negbit, regpart, out);
}

// Round 5
// 112.474 us; speedup vs baseline: 1.9101x; 1.4597x over previous
//
#include <hip/hip_runtime.h>

#define NROWS 12288
#define BSZ   4096
#define DIM   128
#define CSPLIT 16
#define COLS_PER_BLOCK (NROWS / CSPLIT)   // 768
#define NSTRIPS (COLS_PER_BLOCK / 32)     // 24 strips of 32 cols

typedef __bf16 bf16x8 __attribute__((ext_vector_type(8)));
typedef float  f32x4  __attribute__((ext_vector_type(4)));

__device__ __forceinline__ unsigned short f2bf(float f) {
  unsigned int u = __float_as_uint(f);
  u = u + 0x7FFFu + ((u >> 16) & 1u);   // round-to-nearest-even
  return (unsigned short)(u >> 16);
}
__device__ __forceinline__ float bf2f(unsigned short h) {
  return __uint_as_float(((unsigned int)h) << 16);
}

// ---------------------------------------------------------------------------
// Kernel 1 (fused prep + posmax): one wave per triplet index i.
// ---------------------------------------------------------------------------
__global__ void prep_k(const float* __restrict__ a, const float* __restrict__ p,
                       const float* __restrict__ nn,
                       unsigned short* __restrict__ embh, float* __restrict__ sq,
                       unsigned int* __restrict__ negbits,
                       float* __restrict__ posmax2, float* __restrict__ regpart) {
  const int w = threadIdx.x >> 6, lane = threadIdx.x & 63;
  const int i = blockIdx.x * 4 + w;
  const float2 av = reinterpret_cast<const float2*>(a  + (size_t)i * DIM)[lane];
  const float2 pv = reinterpret_cast<const float2*>(p  + (size_t)i * DIM)[lane];
  const float2 nv = reinterpret_cast<const float2*>(nn + (size_t)i * DIM)[lane];

  const unsigned short ha0 = f2bf(av.x), ha1 = f2bf(av.y);
  const unsigned short hp0 = f2bf(pv.x), hp1 = f2bf(pv.y);
  const unsigned short hn0 = f2bf(nv.x), hn1 = f2bf(nv.y);
  reinterpret_cast<ushort2*>(embh + (size_t)i * DIM)[lane]             = make_ushort2(ha0, ha1);
  reinterpret_cast<ushort2*>(embh + (size_t)(BSZ + i) * DIM)[lane]     = make_ushort2(hp0, hp1);
  reinterpret_cast<ushort2*>(embh + (size_t)(2 * BSZ + i) * DIM)[lane] = make_ushort2(hn0, hn1);

  // sq of ROUNDED values (so the GEMM-based d2 is consistent & >= 0)
  float rax = bf2f(ha0), ray = bf2f(ha1);
  float rpx = bf2f(hp0), rpy = bf2f(hp1);
  float rnx = bf2f(hn0), rny = bf2f(hn1);
  float sa = rax * rax + ray * ray;
  float sp = rpx * rpx + rpy * rpy;
  float sn = rnx * rnx + rny * rny;

  // reg from exact values
  float t0 = fabsf(av.x) - 1.f, t1 = fabsf(av.y) - 1.f;
  float t2 = fabsf(pv.x) - 1.f, t3 = fabsf(pv.y) - 1.f;
  float t4 = fabsf(nv.x) - 1.f, t5 = fabsf(nv.y) - 1.f;
  float rg = t0 * t0 + t1 * t1 + t2 * t2 + t3 * t3 + t4 * t4 + t5 * t5;

  // pos distances, exact fp32
  float dx, dy;
  dx = av.x - pv.x; dy = av.y - pv.y; float dap = dx * dx + dy * dy;
  dx = av.x - nv.x; dy = av.y - nv.y; float dan = dx * dx + dy * dy;
  dx = pv.x - nv.x; dy = pv.y - nv.y; float dpn = dx * dx + dy * dy;

  for (int m = 32; m; m >>= 1) {
    sa  += __shfl_xor(sa, m);  sp  += __shfl_xor(sp, m);  sn  += __shfl_xor(sn, m);
    rg  += __shfl_xor(rg, m);
    dap += __shfl_xor(dap, m); dan += __shfl_xor(dan, m); dpn += __shfl_xor(dpn, m);
  }
  if (lane == 0) {
    sq[i] = sa; sq[BSZ + i] = sp; sq[2 * BSZ + i] = sn;
    negbits[i] = negbits[BSZ + i] = negbits[2 * BSZ + i] = 0x7F800000u;  // +inf
    posmax2[i]           = fmaxf(dap, dan);
    posmax2[BSZ + i]     = fmaxf(dap, dpn);
    posmax2[2 * BSZ + i] = fmaxf(dan, dpn);
    regpart[i] = rg;
  }
}

// ---------------------------------------------------------------------------
// Kernel 2: neg_min^2 = fused E*E^T (bf16 MFMA 16x16x32) + row-min.
// Round-5 restructure: waves partition ROWS (64 each); B strips (32 cols,
// 8 KB) are SHARED across the block via async global_load_lds into
// double-buffered LDS (4x less L2 traffic than round 4's per-wave B).
// Depth-2 pipeline: stage(c+1) is issued a full strip before the barrier
// that drains it, so the vmcnt(0)-at-barrier drain finds completed loads.
// Grid (48,16) = 768 blocks; __launch_bounds__(256,3) -> 3 blocks/CU ->
// exactly one dispatch round. Strip rotation desyncs same-column blocks.
// ---------------------------------------------------------------------------
__global__ __launch_bounds__(256, 3) void negmin_k(
    const unsigned short* __restrict__ embh,
    const float* __restrict__ sq,
    unsigned int* __restrict__ negbits) {
  __shared__ __align__(16) char ldsB[2][8192];   // [buf][kc*1024 + lane*16]
  const int tid  = threadIdx.x;
  const int w    = tid >> 6;
  const int lane = tid & 63;
  const int c16  = lane & 15;
  const int q    = lane >> 4;
  const int wRow    = blockIdx.x * 256 + w * 64;   // this wave's 64 rows
  const int colBase = blockIdx.y * COLS_PER_BLOCK;
  const int rot     = blockIdx.x % NSTRIPS;

  // A fragments: 64 rows x K=128. 4 mtiles x 4 ksteps, A[m=c16][k=q*8+j].
  bf16x8 afrag[4][4];
  {
    const char* abase = (const char*)embh + (size_t)(wRow + c16) * 256 + q * 16;
#pragma unroll
    for (int mt = 0; mt < 4; ++mt)
#pragma unroll
      for (int ks = 0; ks < 4; ++ks)
        afrag[mt][ks] = *reinterpret_cast<const bf16x8*>(abase + mt * 4096 + ks * 64);
  }

  float minv[4][4];
#pragma unroll
  for (int mt = 0; mt < 4; ++mt)
#pragma unroll
    for (int r = 0; r < 4; ++r) minv[mt][r] = __builtin_inff();

  // Stage strip sidx into LDS buffer b. 8 chunks of 1 KB; wave w issues
  // chunks 2w, 2w+1. Chunk kc: ks = kc>>1, col-half = kc&1. Dest is
  // wave-uniform base + lane*16 (global_load_lds constraint); the source
  // address per lane is chosen so LDS ends up exactly in B-fragment order.
  auto stage = [&](int sidx, int b) {
#pragma unroll
    for (int h = 0; h < 2; ++h) {
      const int kc = w * 2 + h;
      const char* gp = (const char*)embh +
          (size_t)(colBase + sidx * 32 + (kc & 1) * 16 + c16) * 256 +
          (kc >> 1) * 64 + q * 16;
      __builtin_amdgcn_global_load_lds(
          (const __attribute__((address_space(1))) unsigned int*)gp,
          (__attribute__((address_space(3))) unsigned int*)(&ldsB[b][kc * 1024]),
          16, 0, 0);
    }
  };

  int strip = rot;
  stage(strip, 0);
  __syncthreads();                                  // drain stage(strip 0)
  {
    int s1 = strip + 1; if (s1 >= NSTRIPS) s1 -= NSTRIPS;
    stage(s1, 1);                                   // in flight over compute(0)
  }

  for (int c = 0; c < NSTRIPS; ++c) {
    const int b = c & 1;
    const int colStart = colBase + strip * 32;
    const float sq0 = sq[colStart + c16];
    const float sq1 = sq[colStart + 16 + c16];

    f32x4 acc[4][2] = {};
#pragma unroll
    for (int ks = 0; ks < 4; ++ks)
#pragma unroll
      for (int ct = 0; ct < 2; ++ct) {
        const bf16x8 bfr =
            *reinterpret_cast<const bf16x8*>(&ldsB[b][(ks * 2 + ct) * 1024 + lane * 16]);
#pragma unroll
        for (int mt = 0; mt < 4; ++mt)
          acc[mt][ct] =
              __builtin_amdgcn_mfma_f32_16x16x32_bf16(afrag[mt][ks], bfr, acc[mt][ct], 0, 0, 0);
      }

    // Barrier: (a) all waves done reading buf b -> safe to overwrite;
    // (b) drains each wave's own stage(c+1) loads (issued a full strip ago,
    // ~600 cyc of MFMA to land -> no drain stall).
    __syncthreads();
    if (c + 2 < NSTRIPS) {
      int s2 = strip + 2; if (s2 >= NSTRIPS) s2 -= NSTRIPS;
      stage(s2, b);
    }

    // Epilogue on registers (post-barrier, overlaps stage(c+2) latency).
    // Exclusion j == i (mod 4096): lv = dd + ct*16 + c16 - q*4 vs K = mt*16+r.
    const int dd = (colStart - wRow) & 4095;
    if (dd < 76 || dd > 4064) {
#pragma unroll
      for (int mt = 0; mt < 4; ++mt)
#pragma unroll
        for (int ct = 0; ct < 2; ++ct) {
          const float sqb = ct ? sq1 : sq0;
          const int lvc = dd + ct * 16 + c16 - q * 4;
#pragma unroll
          for (int r = 0; r < 4; ++r) {
            float v = fmaf(-2.f, acc[mt][ct][r], sqb);
            const int K = mt * 16 + r;
            if (lvc == K || lvc == K + 4096) v = __builtin_inff();
            minv[mt][r] = fminf(minv[mt][r], v);
          }
        }
    } else {
#pragma unroll
      for (int mt = 0; mt < 4; ++mt)
#pragma unroll
        for (int ct = 0; ct < 2; ++ct) {
          const float sqb = ct ? sq1 : sq0;
#pragma unroll
          for (int r = 0; r < 4; ++r)
            minv[mt][r] = fminf(minv[mt][r], fmaf(-2.f, acc[mt][ct][r], sqb));
        }
    }

    strip = strip + 1; if (strip >= NSTRIPS) strip -= NSTRIPS;
  }

  // Reduce over the 16 column-lanes sharing each row, then atomicMin (uint
  // bits order-preserving for floats >= 0). 64 rows per wave.
#pragma unroll
  for (int mt = 0; mt < 4; ++mt)
#pragma unroll
    for (int r = 0; r < 4; ++r) {
      float v = minv[mt][r];
      v = fminf(v, __shfl_xor(v, 1));
      v = fminf(v, __shfl_xor(v, 2));
      v = fminf(v, __shfl_xor(v, 4));
      v = fminf(v, __shfl_xor(v, 8));
      if (c16 == 0) {
        const int row = wRow + mt * 16 + q * 4 + r;   // C/D: row=(lane>>4)*4+r
        float d2 = sq[row] + v;
        d2 = fmaxf(d2, 0.f);
        atomicMin(&negbits[row], __float_as_uint(d2));
      }
    }
}

// ---------------------------------------------------------------------------
// Kernel 3: final scalar reduction. Single block, 1024 threads.
// ---------------------------------------------------------------------------
__global__ void final_k(const float* __restrict__ posmax2,
                        const unsigned int* __restrict__ negbits,
                        const float* __restrict__ regpart, float* __restrict__ out) {
  __shared__ float red[16], redr[16];
  const int tid = threadIdx.x;  // 1024
  float s = 0.f;
  for (int i = tid; i < NROWS; i += 1024) {
    const float pm = sqrtf(posmax2[i]);
    const float nm = sqrtf(__uint_as_float(negbits[i]));
    s += fmaxf(pm - nm + 0.4f, 0.f);
  }
  float rg = 0.f;
  for (int i = tid; i < BSZ; i += 1024) rg += regpart[i];
  for (int m = 32; m; m >>= 1) { s += __shfl_xor(s, m); rg += __shfl_xor(rg, m); }
  if ((tid & 63) == 0) { red[tid >> 6] = s; redr[tid >> 6] = rg; }
  __syncthreads();
  if (tid == 0) {
    float t = 0.f, tr = 0.f;
#pragma unroll
    for (int k = 0; k < 16; ++k) { t += red[k]; tr += redr[k]; }
    out[0] = t / (float)NROWS + 0.01f * (tr / (float)(NROWS * DIM));
  }
}

// ---------------------------------------------------------------------------
extern "C" void kernel_launch(void* const* d_in, const int* in_sizes, int n_in,
                              void* d_out, int out_size, void* d_ws, size_t ws_size,
                              hipStream_t stream) {
  const float* a  = (const float*)d_in[0];
  const float* p  = (const float*)d_in[1];
  const float* nn = (const float*)d_in[2];
  float* out = (float*)d_out;
  char* ws = (char*)d_ws;

  const size_t EMBH_BYTES = (size_t)NROWS * DIM * 2;       // 3,145,728
  unsigned short* embh    = (unsigned short*)ws;
  float*          sq      = (float*)(ws + EMBH_BYTES);
  unsigned int*   negbit  = (unsigned int*)(ws + EMBH_BYTES + (size_t)NROWS * 4);
  float*          pos2    = (float*)(ws + EMBH_BYTES + (size_t)NROWS * 8);
  float*          regpart = (float*)(ws + EMBH_BYTES + (size_t)NROWS * 12);

  prep_k<<<BSZ / 4, 256, 0, stream>>>(a, p, nn, embh, sq, negbit, pos2, regpart);
  negmin_k<<<dim3(NROWS / 256, CSPLIT), 256, 0, stream>>>(embh, sq, negbit);
  final_k<<<1, 1024, 0, stream>>>(pos2, negbit, regpart, out);
}